// Round 2
// baseline (595.815 us; speedup 1.0000x reference)
//
#include <hip/hip_runtime.h>

// SpikingConv2D: tj [16,258,258] f32, kernel [128,1,3,3] f32 (flat 9x128 view),
// D_i [9,128] f32 (row 0 only). out[n*128+f], n=(i*256+j)*16+b, Hv=256.
// ti = sum_t x[t]*W[t][f] + (1 - D_i[0][f]), clamped to <= 1.0.
// Write-BW bound: 512 MB output. Strategy: 4 rows/thread for 36 loads in
// flight (latency hiding), non-temporal stores (don't thrash L2; tj stays
// L2-resident), int32 addressing throughout.

#define B_N   16
#define S_N   258
#define HV_N  256
#define F_N   128

typedef float v4f __attribute__((ext_vector_type(4)));

__global__ __launch_bounds__(256, 4) void spiking_conv2d_kernel(
    const float* __restrict__ tj, const float* __restrict__ kern,
    const float* __restrict__ Di, float* __restrict__ out, int num_groups) {
  const int fq   = threadIdx.x & 31;  // filter quad: f = 4*fq .. 4*fq+3
  const int nsub = threadIdx.x >> 5;  // 0..7

  // W[t][f] = kern_flat[t*128 + f]  (raw view(9,128)); loaded once per thread.
  float4 w[9];
#pragma unroll
  for (int t = 0; t < 9; ++t)
    w[t] = reinterpret_cast<const float4*>(kern)[t * (F_N / 4) + fq];
  const float4 d = reinterpret_cast<const float4*>(Di)[fq];
  const float4 thr = make_float4(1.0f - d.x, 1.0f - d.y, 1.0f - d.z, 1.0f - d.w);

  for (int g = blockIdx.x; g < num_groups; g += gridDim.x) {
    // Block iteration covers 32 consecutive n; this thread takes 4:
    // n0..n0+3 (n0 multiple of 4 -> same pixel, batches b0..b0+3).
    const int n0  = g * 32 + nsub * 4;
    const int b0  = n0 & (B_N - 1);        // in {0,4,8,12}
    const int pix = n0 >> 4;
    const int j   = pix & (HV_N - 1);
    const int i   = pix >> 8;

    const float* base = tj + (b0 * S_N + i) * S_N + j;  // fits int32
    float x[4][9];
#pragma unroll
    for (int r = 0; r < 4; ++r) {
      const float* p = base + r * (S_N * S_N);
#pragma unroll
      for (int ki = 0; ki < 3; ++ki)
#pragma unroll
        for (int kj = 0; kj < 3; ++kj)
          x[r][ki * 3 + kj] = p[ki * S_N + kj];  // 36 independent loads in flight
    }

    // out float4 index: n*32 + fq  (max 33.5M, fits int32)
    v4f* outv = reinterpret_cast<v4f*>(out) + n0 * (F_N / 4) + fq;
#pragma unroll
    for (int r = 0; r < 4; ++r) {
      float4 acc = thr;
#pragma unroll
      for (int t = 0; t < 9; ++t) {
        acc.x = fmaf(x[r][t], w[t].x, acc.x);
        acc.y = fmaf(x[r][t], w[t].y, acc.y);
        acc.z = fmaf(x[r][t], w[t].z, acc.z);
        acc.w = fmaf(x[r][t], w[t].w, acc.w);
      }
      v4f v = {fminf(acc.x, 1.0f), fminf(acc.y, 1.0f),
               fminf(acc.z, 1.0f), fminf(acc.w, 1.0f)};
      __builtin_nontemporal_store(v, outv + r * (F_N / 4));
    }
  }
}

extern "C" void kernel_launch(void* const* d_in, const int* in_sizes, int n_in,
                              void* d_out, int out_size, void* d_ws, size_t ws_size,
                              hipStream_t stream) {
  const float* tj   = (const float*)d_in[0];
  const float* kern = (const float*)d_in[1];
  const float* Di   = (const float*)d_in[2];
  float* out = (float*)d_out;

  const int num_groups = (HV_N * HV_N * B_N) / 32;  // 32768 groups of 32 rows
  const int grid = 4096;                            // 8 iters/block, 16 blocks/CU
  spiking_conv2d_kernel<<<grid, 256, 0, stream>>>(tj, kern, Di, out, num_groups);
}

// Round 3
// 575.197 us; speedup vs baseline: 1.0358x; 1.0358x over previous
//
#include <hip/hip_runtime.h>

// SpikingConv2D: tj [16,258,258] f32, kernel [128,1,3,3] f32 (flat 9x128 view),
// D_i [9,128] f32 (row 0 only). out[n*128+f], n=(i*256+j)*16+b, Hv=256.
// ti = min(sum_t x[t]*W[t][f] + (1 - D_i[0][f]), 1.0).
//
// Bench anatomy (R2): timed graph carries ~430us of harness poison fills
// (2GB d_ws + 512MB d_out); our kernel is the remaining ~150-165us vs a
// ~88us write floor (the d_out fill itself). tj (4.3MB) exceeds one XCD's
// 4MiB L2 -> loads are L3-latency (~400+cyc); hide with occupancy, not ILP:
// 1 row/thread (~60 VGPR), launch_bounds(256,6) -> 6 waves/SIMD.

#define B_N   16
#define S_N   258
#define HV_N  256
#define F_N   128

typedef float v4f __attribute__((ext_vector_type(4)));

__global__ __launch_bounds__(256, 6) void spiking_conv2d_kernel(
    const float* __restrict__ tj, const float* __restrict__ kern,
    const float* __restrict__ Di, float* __restrict__ out, int num_groups) {
  const int fq   = threadIdx.x & 31;  // filter quad: f = 4*fq .. 4*fq+3
  const int nsub = threadIdx.x >> 5;  // 0..7: row within group of 8

  // W[t][f] = kern_flat[t*128 + f]  (raw view(9,128)); registers, loaded once.
  float4 w[9];
#pragma unroll
  for (int t = 0; t < 9; ++t)
    w[t] = reinterpret_cast<const float4*>(kern)[t * (F_N / 4) + fq];
  const float4 d = reinterpret_cast<const float4*>(Di)[fq];
  const float4 thr = make_float4(1.0f - d.x, 1.0f - d.y, 1.0f - d.z, 1.0f - d.w);

  for (int g = blockIdx.x; g < num_groups; g += gridDim.x) {
    const int n   = g * 8 + nsub;        // row id: n = (i*256+j)*16 + b
    const int b   = n & (B_N - 1);
    const int pix = n >> 4;
    const int j   = pix & (HV_N - 1);
    const int i   = pix >> 8;

    const float* base = tj + (b * S_N + i) * S_N + j;  // int32 arithmetic
    float x[9];
#pragma unroll
    for (int ki = 0; ki < 3; ++ki)
#pragma unroll
      for (int kj = 0; kj < 3; ++kj)
        x[ki * 3 + kj] = base[ki * S_N + kj];  // 9 loads in flight, L2/L3 hits

    float4 acc = thr;
#pragma unroll
    for (int t = 0; t < 9; ++t) {
      acc.x = fmaf(x[t], w[t].x, acc.x);
      acc.y = fmaf(x[t], w[t].y, acc.y);
      acc.z = fmaf(x[t], w[t].z, acc.z);
      acc.w = fmaf(x[t], w[t].w, acc.w);
    }
    v4f v = {fminf(acc.x, 1.0f), fminf(acc.y, 1.0f),
             fminf(acc.z, 1.0f), fminf(acc.w, 1.0f)};
    // out float4 index n*32+fq: wave writes 2x512B contiguous per store.
    __builtin_nontemporal_store(v, reinterpret_cast<v4f*>(out) + n * (F_N / 4) + fq);
  }
}

extern "C" void kernel_launch(void* const* d_in, const int* in_sizes, int n_in,
                              void* d_out, int out_size, void* d_ws, size_t ws_size,
                              hipStream_t stream) {
  const float* tj   = (const float*)d_in[0];
  const float* kern = (const float*)d_in[1];
  const float* Di   = (const float*)d_in[2];
  float* out = (float*)d_out;

  const int num_groups = (HV_N * HV_N * B_N) / 8;  // 131072 groups of 8 rows
  const int grid = 8192;                           // 16 iters/block
  spiking_conv2d_kernel<<<grid, 256, 0, stream>>>(tj, kern, Di, out, num_groups);
}